// Round 1
// baseline (891.308 us; speedup 1.0000x reference)
//
#include <hip/hip_runtime.h>

typedef unsigned short bfu;                                     // bf16 storage
typedef __attribute__((ext_vector_type(8))) __bf16 bf16x8;      // MFMA A/B frag
typedef __attribute__((ext_vector_type(4))) float f32x4;        // MFMA C/D frag

__device__ __forceinline__ float bf2f(bfu u) {
    unsigned int x = ((unsigned int)u) << 16;
    return __builtin_bit_cast(float, x);
}
__device__ __forceinline__ bfu f2bf(float f) {  // round-nearest-even
    unsigned int u = __builtin_bit_cast(unsigned int, f);
    unsigned int r = (u + 0x7fffu + ((u >> 16) & 1u)) >> 16;
    return (bfu)r;
}
__device__ __forceinline__ float sigm(float x) { return 1.0f / (1.0f + __expf(-x)); }
__device__ __forceinline__ float gelu_f(float x) {
    return 0.5f * x * (1.0f + erff(x * 0.70710678118654752f));  // exact-erf GELU
}

// async global->LDS, 16B per lane; LDS dest = wave-uniform base + lane*16
__device__ __forceinline__ void async16(const void* g, void* l) {
    __builtin_amdgcn_global_load_lds((const __attribute__((address_space(1))) void*)g,
                                     (__attribute__((address_space(3))) void*)l, 16, 0, 0);
}

// ---------------------------------------------------------------- transpose
// fp32 [K][N] -> bf16 [N][K]; all K,N are multiples of 64. 9 matrices batched.
struct TDesc { const float* src; bfu* dst; int K, N, blk0; };
struct TPack { TDesc d[9]; };

__global__ __launch_bounds__(256) void transpose_k(TPack p) {
    const int bid = blockIdx.x;
    int j = 0;
#pragma unroll
    for (int i = 1; i < 9; ++i)
        if (bid >= p.d[i].blk0) j = i;
    const TDesc d = p.d[j];
    const int local = bid - d.blk0;
    const int tkn = d.K >> 6;
    const int tk = local % tkn, tn = local / tkn;
    const int k0 = tk * 64, n0 = tn * 64;
    __shared__ float tile[64][65];  // +1 pad: conflict-free transpose read
    const int tx = threadIdx.x & 63, ty = threadIdx.x >> 6;
#pragma unroll
    for (int i = 0; i < 16; ++i) {
        const int r = ty * 16 + i;
        tile[r][tx] = d.src[(size_t)(k0 + r) * d.N + n0 + tx];
    }
    __syncthreads();
#pragma unroll
    for (int i = 0; i < 16; ++i) {
        const int n = ty * 16 + i;
        d.dst[(size_t)(n0 + n) * d.K + k0 + tx] = f2bf(tile[tx][n]);
    }
}

// ------------------------------------------------------- geometric + cast
// one wave per row of 768 fp32: geometric quality (out rows), bf16 cast,
// and (cq+dq)/3 partial of the information head (phase 1 only).
__global__ __launch_bounds__(256)
void geomcast_k(const float* F0, const float* F1, bfu* D0, bfu* D1,
                float* g0, float* g1, float* p0, float* p1) {
    const int z = blockIdx.y;
    const float* F = z ? F1 : F0;
    bfu* D = z ? D1 : D0;
    float* gout = z ? g1 : g0;
    float* part = z ? p1 : p0;
    const int wave = threadIdx.x >> 6, lane = threadIdx.x & 63;
    const int row = blockIdx.x * 4 + wave;
    const float* fr = F + (size_t)row * 768;
    bfu* dr = D + (size_t)row * 768;
    float sum = 0.f, ss = 0.f, cnt = 0.f;
#pragma unroll
    for (int i = 0; i < 3; ++i) {
        const float4 v = *(const float4*)(fr + i * 256 + lane * 4);
        sum += v.x + v.y + v.z + v.w;
        ss += v.x * v.x + v.y * v.y + v.z * v.z + v.w * v.w;
        cnt += ((fabsf(v.x) > 0.01f) ? 1.f : 0.f) + ((fabsf(v.y) > 0.01f) ? 1.f : 0.f) +
               ((fabsf(v.z) > 0.01f) ? 1.f : 0.f) + ((fabsf(v.w) > 0.01f) ? 1.f : 0.f);
        ushort4 b;
        b.x = f2bf(v.x); b.y = f2bf(v.y); b.z = f2bf(v.z); b.w = f2bf(v.w);
        *(ushort4*)(dr + i * 256 + lane * 4) = b;
    }
#pragma unroll
    for (int off = 32; off; off >>= 1) {
        sum += __shfl_xor(sum, off);
        ss  += __shfl_xor(ss, off);
        cnt += __shfl_xor(cnt, off);
    }
    if (lane == 0) {
        const float n = sqrtf(ss);
        const float nq = sigm((n - 1.f) * 2.f);
        const float sp = cnt * (1.f / 768.f);
        float var = (ss - sum * sum * (1.f / 768.f)) * (1.f / 767.f);
        var = fmaxf(var, 0.f);
        const float sq = sigm(sqrtf(var) * 10.f - 1.f);  // torch.std ddof=1
        gout[row] = (nq + sp + sq) * (1.f / 3.f);
        if (part) {
            const float cq = (n > 0.01f) ? (1.f / 768.f) : 0.f;
            const float nc = fmaxf(n, 1e-12f);
            const float dq = sigm(ss / (nc * nc) - 0.5f);
            part[row] = (cq + dq) * (1.f / 3.f);
        }
    }
}

// ------------------------------------------------------------------- GEMM
// C[M,N] = act(A[M,K] @ W[K,N] + bias), W pre-transposed bf16 [N][K].
// A is bf16 [M,lda]; cols >= Ksplit come from A2 (for the 2H concat heads).
// BM=128, BK=64; BN=128: 4 waves as 2x2, each 64x64 (4x4 MFMA tiles);
// BN=64: 4 waves as 4x1, each 32x64 (2x4 tiles). m97-style staging.
struct GArg { const bfu* A; const bfu* A2; const bfu* Wt; const float* bias; bfu* Cb; float* Cf; };

template <int BN>
__global__ __launch_bounds__(256)
void gemm_k(GArg ga, GArg gb, int M, int N, int K, int Ksplit, int lda, int act) {
    constexpr int BM = 128, BK = 64;
    constexpr int MT = (BN == 128) ? 4 : 2;
    constexpr int NT = 4;
    __shared__ bfu As[BM * BK];
    __shared__ bfu Ws[BN * BK];
    const GArg g = blockIdx.z ? gb : ga;
    const int t = threadIdx.x;
    const int wave = t >> 6, lane = t & 63;
    const int row_l = lane & 15, kq = lane >> 4;
    const int m0 = blockIdx.x * BM;
    const int n0 = blockIdx.y * BN;
    const int wm = (BN == 128) ? (wave >> 1) : wave;
    const int wn = (BN == 128) ? (wave & 1) : 0;
    const int wrow0 = wm * (MT * 16);
    const int wcol0 = wn * 64;

    f32x4 acc[MT][NT] = {};

    const int nkt = K / BK;
    for (int kt = 0; kt < nkt; ++kt) {
        const int k0 = kt * BK;
        const bfu* Ab;
        int kc;
        if (k0 < Ksplit) { Ab = g.A; kc = k0; }
        else             { Ab = g.A2; kc = k0 - Ksplit; }
        // stage A tile (BM x BK): 16B/lane chunks, LDS order == chunk order
#pragma unroll
        for (int i = 0; i < (BM * BK) / (8 * 256); ++i) {
            const int c = i * 256 + t;
            const int r = c >> 3, cc = (c & 7) << 3;
            async16(Ab + (size_t)(m0 + r) * lda + kc + cc, As + ((i * 256 + wave * 64) << 3));
        }
        // stage W tile (BN x BK) from [N][K] layout
#pragma unroll
        for (int i = 0; i < (BN * BK) / (8 * 256); ++i) {
            const int c = i * 256 + t;
            const int r = c >> 3, cc = (c & 7) << 3;
            async16(g.Wt + (size_t)(n0 + r) * K + k0 + cc, Ws + ((i * 256 + wave * 64) << 3));
        }
        __syncthreads();
#pragma unroll
        for (int ks = 0; ks < 2; ++ks) {
            bf16x8 af[MT], bfr[NT];
#pragma unroll
            for (int mi = 0; mi < MT; ++mi)
                af[mi] = *(const bf16x8*)(As + (wrow0 + mi * 16 + row_l) * BK + ks * 32 + kq * 8);
#pragma unroll
            for (int ni = 0; ni < NT; ++ni)
                bfr[ni] = *(const bf16x8*)(Ws + (wcol0 + ni * 16 + row_l) * BK + ks * 32 + kq * 8);
#pragma unroll
            for (int mi = 0; mi < MT; ++mi)
#pragma unroll
                for (int ni = 0; ni < NT; ++ni)
                    acc[mi][ni] = __builtin_amdgcn_mfma_f32_16x16x32_bf16(af[mi], bfr[ni], acc[mi][ni], 0, 0, 0);
        }
        __syncthreads();
    }

    // epilogue: C/D layout col=lane&15, row=quad*4+reg (verified m89/m91)
#pragma unroll
    for (int ni = 0; ni < NT; ++ni) {
        const int col = n0 + wcol0 + ni * 16 + row_l;
        const float bv = g.bias[col];
#pragma unroll
        for (int mi = 0; mi < MT; ++mi) {
#pragma unroll
            for (int r = 0; r < 4; ++r) {
                const int row = m0 + wrow0 + mi * 16 + kq * 4 + r;
                float v = acc[mi][ni][r] + bv;
                if (act) v = gelu_f(v);
                const size_t idx = (size_t)row * N + col;
                if (g.Cb) g.Cb[idx] = f2bf(v);
                else      g.Cf[idx] = v;
            }
        }
    }
    (void)M;
}

// ----------------------------------------------------------- entropy head
// wave per row: 64 fp32 logits -> round(sig*10) -> histogram entropy.
__global__ __launch_bounds__(256)
void entropy_k(const float* E0, const float* E1, const float* p0, const float* p1,
               float* o0, float* o1) {
    const int z = blockIdx.y;
    const float* E = z ? E1 : E0;
    const float* part = z ? p1 : p0;
    float* o = z ? o1 : o0;
    const int wave = threadIdx.x >> 6, lane = threadIdx.x & 63;
    const int row = blockIdx.x * 4 + wave;
    const float e = E[(size_t)row * 64 + lane];
    const int d = (int)rintf(sigm(e) * 10.f);  // np.round = half-to-even = rintf
    float ent = 0.f;
#pragma unroll
    for (int b = 0; b <= 10; ++b) {
        const unsigned long long m = __ballot(d == b);
        const int c = __popcll(m);
        if (c > 0) {
            const float p = (float)c * (1.f / 64.f);
            ent -= p * __logf(p + 1e-8f);
        }
    }
    if (lane == 0) o[row] = part[row] + sigm(ent - 2.f) * (1.f / 3.f);
}

// -------------------------------------------------- final N->1 dot+sigmoid
__global__ __launch_bounds__(256)
void rowdot_k(const bfu* H0, const bfu* H1, const float* w0, const float* w1,
              const float* b0, const float* b1, float* o0, float* o1, int N) {
    const int z = blockIdx.y;
    const bfu* Hh = z ? H1 : H0;
    const float* w = z ? w1 : w0;
    const float* bp = z ? b1 : b0;
    float* o = z ? o1 : o0;
    const int wave = threadIdx.x >> 6, lane = threadIdx.x & 63;
    const int row = blockIdx.x * 4 + wave;
    const bfu* hr = Hh + (size_t)row * N;
    float s = 0.f;
    for (int k = lane; k < N; k += 64) s += bf2f(hr[k]) * w[k];
#pragma unroll
    for (int off = 32; off; off >>= 1) s += __shfl_xor(s, off);
    if (lane == 0) o[row] = sigm(s + bp[0]);
}

__global__ __launch_bounds__(256) void finalize_k(float* out, int B) {
    const int i = blockIdx.x * 256 + threadIdx.x;
    if (i < B) {
        const float v = out[0 * B + i] + out[1 * B + i] + out[4 * B + i] + out[5 * B + i] +
                        out[7 * B + i] + 0.5f * (out[8 * B + i] + out[9 * B + i]);
        out[17 * B + i] = v * (1.f / 6.f);
    }
}

extern "C" void kernel_launch(void* const* d_in, const int* in_sizes, int n_in,
                              void* d_out, int out_size, void* d_ws, size_t ws_size,
                              hipStream_t stream) {
    const int B = in_sizes[4];  // 16384
    float* out = (float*)d_out;
    const float* img  = (const float*)d_in[0];
    const float* txt  = (const float*)d_in[1];
    const float* eimg = (const float*)d_in[2];
    const float* etxt = (const float*)d_in[3];
    const float* info_w1 = (const float*)d_in[5];  const float* info_b1 = (const float*)d_in[6];
    const float* info_w2 = (const float*)d_in[7];  const float* info_b2 = (const float*)d_in[8];
    const float* imp_w1  = (const float*)d_in[9];  const float* imp_b1  = (const float*)d_in[10];
    const float* imp_w2  = (const float*)d_in[11]; const float* imp_b2  = (const float*)d_in[12];
    const float* disc_w1 = (const float*)d_in[13]; const float* disc_b1 = (const float*)d_in[14];
    const float* disc_w2 = (const float*)d_in[15]; const float* disc_b2 = (const float*)d_in[16];
    const float* disc_w3 = (const float*)d_in[17]; const float* disc_b3 = (const float*)d_in[18];
    const float* cons_w1 = (const float*)d_in[19]; const float* cons_b1 = (const float*)d_in[20];
    const float* cons_w2 = (const float*)d_in[21]; const float* cons_b2 = (const float*)d_in[22];
    const float* cons_w3 = (const float*)d_in[23]; const float* cons_b3 = (const float*)d_in[24];
    const float* diff_w1 = (const float*)d_in[25]; const float* diff_b1 = (const float*)d_in[26];
    const float* diff_w2 = (const float*)d_in[27]; const float* diff_b2 = (const float*)d_in[28];
    const float* diff_w3 = (const float*)d_in[29]; const float* diff_b3 = (const float*)d_in[30];

    char* wsp = (char*)d_ws;
    size_t off = 0;
    auto alloc = [&](size_t bytes) -> void* {
        void* p = wsp + off;
        off += (bytes + 255) & ~(size_t)255;
        return p;
    };
    bfu* info1t = (bfu*)alloc((size_t)256 * 768 * 2);
    bfu* info2t = (bfu*)alloc((size_t)64 * 256 * 2);
    bfu* imp1t  = (bfu*)alloc((size_t)384 * 768 * 2);
    bfu* disc1t = (bfu*)alloc((size_t)256 * 768 * 2);
    bfu* disc2t = (bfu*)alloc((size_t)64 * 256 * 2);
    bfu* cons1t = (bfu*)alloc((size_t)768 * 1536 * 2);
    bfu* cons2t = (bfu*)alloc((size_t)384 * 768 * 2);
    bfu* diff1t = (bfu*)alloc((size_t)768 * 1536 * 2);
    bfu* diff2t = (bfu*)alloc((size_t)384 * 768 * 2);
    bfu* fA0 = (bfu*)alloc((size_t)B * 768 * 2);
    bfu* fA1 = (bfu*)alloc((size_t)B * 768 * 2);
    bfu* h1a = (bfu*)alloc((size_t)B * 768 * 2);
    bfu* h1b = (bfu*)alloc((size_t)B * 768 * 2);
    bfu* h2a = (bfu*)alloc((size_t)B * 384 * 2);
    bfu* h2b = (bfu*)alloc((size_t)B * 384 * 2);
    float* part0 = (float*)alloc((size_t)B * 4);
    float* part1 = (float*)alloc((size_t)B * 4);
    (void)ws_size; (void)n_in; (void)out_size;  // need ~133.4 MB of ws

    // ---- weight prep (every call: ws is re-poisoned) ----
    TPack tp;
    int blk = 0, ti = 0;
    auto setd = [&](const float* s, bfu* d, int K, int N) {
        tp.d[ti++] = {s, d, K, N, blk};
        blk += (K / 64) * (N / 64);
    };
    setd(info_w1, info1t, 768, 256);
    setd(info_w2, info2t, 256, 64);
    setd(imp_w1, imp1t, 768, 384);
    setd(disc_w1, disc1t, 768, 256);
    setd(disc_w2, disc2t, 256, 64);
    setd(cons_w1, cons1t, 1536, 768);
    setd(cons_w2, cons2t, 768, 384);
    setd(diff_w1, diff1t, 1536, 768);
    setd(diff_w2, diff2t, 768, 384);
    transpose_k<<<dim3(blk), 256, 0, stream>>>(tp);

    const dim3 rowsB(B / 4, 2), rows1(B / 4, 1);

    // ================= phase 1: image_feat / text_feat =================
    geomcast_k<<<rowsB, 256, 0, stream>>>(img, txt, fA0, fA1, out + 0 * B, out + 1 * B, part0, part1);
    {   // info layer1: 768->256 gelu
        GArg a{fA0, nullptr, info1t, info_b1, h1a, nullptr}, b{fA1, nullptr, info1t, info_b1, h1b, nullptr};
        gemm_k<128><<<dim3(B / 128, 2, 2), 256, 0, stream>>>(a, b, B, 256, 768, 768, 768, 1);
    }
    {   // info layer2: 256->64, no act, fp32 out
        GArg a{h1a, nullptr, info2t, info_b2, nullptr, (float*)h2a}, b{h1b, nullptr, info2t, info_b2, nullptr, (float*)h2b};
        gemm_k<64><<<dim3(B / 128, 1, 2), 256, 0, stream>>>(a, b, B, 64, 256, 256, 256, 0);
    }
    entropy_k<<<rowsB, 256, 0, stream>>>((float*)h2a, (float*)h2b, part0, part1, out + 4 * B, out + 5 * B);
    {   // importance: 768->384 gelu
        GArg a{fA0, nullptr, imp1t, imp_b1, h1a, nullptr}, b{fA1, nullptr, imp1t, imp_b1, h1b, nullptr};
        gemm_k<128><<<dim3(B / 128, 3, 2), 256, 0, stream>>>(a, b, B, 384, 768, 768, 768, 1);
    }
    rowdot_k<<<rowsB, 256, 0, stream>>>(h1a, h1b, imp_w2, imp_w2, imp_b2, imp_b2, out + 8 * B, out + 9 * B, 384);
    {   // disc layer1: 768->256 gelu
        GArg a{fA0, nullptr, disc1t, disc_b1, h1a, nullptr}, b{fA1, nullptr, disc1t, disc_b1, h1b, nullptr};
        gemm_k<128><<<dim3(B / 128, 2, 2), 256, 0, stream>>>(a, b, B, 256, 768, 768, 768, 1);
    }
    {   // disc layer2: 256->64 gelu
        GArg a{h1a, nullptr, disc2t, disc_b2, h2a, nullptr}, b{h1b, nullptr, disc2t, disc_b2, h2b, nullptr};
        gemm_k<64><<<dim3(B / 128, 1, 2), 256, 0, stream>>>(a, b, B, 64, 256, 256, 256, 1);
    }
    rowdot_k<<<rowsB, 256, 0, stream>>>(h2a, h2b, disc_w3, disc_w3, disc_b3, disc_b3, out + 12 * B, out + 14 * B, 64);
    {   // cons_o layer1: concat(img,txt) 1536->768 gelu
        GArg a{fA0, fA1, cons1t, cons_b1, h1a, nullptr};
        GArg b = a;
        gemm_k<128><<<dim3(B / 128, 6, 1), 256, 0, stream>>>(a, b, B, 768, 1536, 768, 768, 1);
    }
    {   // cons_o layer2: 768->384 gelu
        GArg a{h1a, nullptr, cons2t, cons_b2, h2a, nullptr};
        GArg b = a;
        gemm_k<128><<<dim3(B / 128, 3, 1), 256, 0, stream>>>(a, b, B, 384, 768, 768, 768, 1);
    }
    rowdot_k<<<rows1, 256, 0, stream>>>(h2a, h2a, cons_w3, cons_w3, cons_b3, cons_b3, out + 6 * B, out + 6 * B, 384);

    // ============ phase 2: enhanced_image_feat / enhanced_text_feat ============
    geomcast_k<<<rowsB, 256, 0, stream>>>(eimg, etxt, fA0, fA1, out + 2 * B, out + 3 * B, nullptr, nullptr);
    {   // importance
        GArg a{fA0, nullptr, imp1t, imp_b1, h1a, nullptr}, b{fA1, nullptr, imp1t, imp_b1, h1b, nullptr};
        gemm_k<128><<<dim3(B / 128, 3, 2), 256, 0, stream>>>(a, b, B, 384, 768, 768, 768, 1);
    }
    rowdot_k<<<rowsB, 256, 0, stream>>>(h1a, h1b, imp_w2, imp_w2, imp_b2, imp_b2, out + 10 * B, out + 11 * B, 384);
    {   // disc layer1
        GArg a{fA0, nullptr, disc1t, disc_b1, h1a, nullptr}, b{fA1, nullptr, disc1t, disc_b1, h1b, nullptr};
        gemm_k<128><<<dim3(B / 128, 2, 2), 256, 0, stream>>>(a, b, B, 256, 768, 768, 768, 1);
    }
    {   // disc layer2
        GArg a{h1a, nullptr, disc2t, disc_b2, h2a, nullptr}, b{h1b, nullptr, disc2t, disc_b2, h2b, nullptr};
        gemm_k<64><<<dim3(B / 128, 1, 2), 256, 0, stream>>>(a, b, B, 64, 256, 256, 256, 1);
    }
    rowdot_k<<<rowsB, 256, 0, stream>>>(h2a, h2b, disc_w3, disc_w3, disc_b3, disc_b3, out + 13 * B, out + 15 * B, 64);
    {   // cons_e + diff layer1 (z-batched, same A pair, different W)
        GArg a{fA0, fA1, cons1t, cons_b1, h1a, nullptr}, b{fA0, fA1, diff1t, diff_b1, h1b, nullptr};
        gemm_k<128><<<dim3(B / 128, 6, 2), 256, 0, stream>>>(a, b, B, 768, 1536, 768, 768, 1);
    }
    {   // cons_e + diff layer2
        GArg a{h1a, nullptr, cons2t, cons_b2, h2a, nullptr}, b{h1b, nullptr, diff2t, diff_b2, h2b, nullptr};
        gemm_k<128><<<dim3(B / 128, 3, 2), 256, 0, stream>>>(a, b, B, 384, 768, 768, 768, 1);
    }
    rowdot_k<<<rowsB, 256, 0, stream>>>(h2a, h2b, cons_w3, diff_w3, cons_b3, diff_b3, out + 7 * B, out + 16 * B, 384);

    finalize_k<<<dim3((B + 255) / 256), 256, 0, stream>>>(out, B);
}